// Round 2
// baseline (6397.893 us; speedup 1.0000x reference)
//
#include <hip/hip_runtime.h>
#include <stdint.h>

// EncDecAD: encoder LSTM (256) -> Linear -> self-feeding decoder LSTM (256).
// Persistent: 256 blocks (1/CU), 16 groups x 16 blocks; group = 32 batch rows,
// block = 16 h-cols. Weights resident as MFMA B-frags in VGPRs.
// R5:
//  (a) LDS staging of peer-h: ONE 16KB cooperative load per block per step
//      (was 4 waves x 16KB redundant coherent loads) -> 4x less exchange
//      traffic on either protocol. XOR-swizzled LDS (chunk ^= row&7) for
//      conflict-free ds_read_b128 frags.
//  (b) XCD-L2 fast path, now gated by a runtime sc0 visibility SELF-TEST
//      (bounded), after XCC-ID consensus; verdicts exchanged at agent scope
//      so the whole group takes the same branch. All fast polls bounded at
//      50k iters -> no multi-second hang even if coherence assumptions fail.
//  (c) All inline-asm operands are u32x4 / uint64_t (no i16-vector
//      constraints). Slow path = proven R3 agent-scope protocol + staging.
// Numerics bitwise-identical to R3 (decoder t0 keeps original MFMA order via
// a second stage buffer).

#define H_ 256
#define B_ 512
#define T_ 256

typedef short short8 __attribute__((ext_vector_type(8)));
typedef float f32x4 __attribute__((ext_vector_type(4)));
typedef uint32_t u32x4 __attribute__((ext_vector_type(4)));

__device__ __forceinline__ short f2bf(float f) {
  union { float f; uint32_t u; } v; v.f = f;
  uint32_t r = (v.u + 0x7FFFu + ((v.u >> 16) & 1u)) >> 16;  // RNE
  return (short)(uint16_t)r;
}

__device__ __forceinline__ short8 load8f_bf(const float* __restrict__ p) {
  const float4 a = *(const float4*)p;
  const float4 b = *(const float4*)(p + 4);
  short8 r;
  r[0]=f2bf(a.x); r[1]=f2bf(a.y); r[2]=f2bf(a.z); r[3]=f2bf(a.w);
  r[4]=f2bf(b.x); r[5]=f2bf(b.y); r[6]=f2bf(b.z); r[7]=f2bf(b.w);
  return r;
}

__device__ __forceinline__ short8 load8f_bf_sum(const float* __restrict__ p,
                                                const float* __restrict__ q) {
  const float4 a = *(const float4*)p, b = *(const float4*)(p + 4);
  const float4 c = *(const float4*)q, d = *(const float4*)(q + 4);
  short8 r;
  r[0]=f2bf(a.x+c.x); r[1]=f2bf(a.y+c.y); r[2]=f2bf(a.z+c.z); r[3]=f2bf(a.w+c.w);
  r[4]=f2bf(b.x+d.x); r[5]=f2bf(b.y+d.y); r[6]=f2bf(b.z+d.z); r[7]=f2bf(b.w+d.w);
  return r;
}

// tie 4 staged loads through a vmcnt fence before their ds_write consumers
__device__ __forceinline__ void fence4u(u32x4 (&a)[4]) {
  asm volatile("s_waitcnt vmcnt(0)"
               : "+v"(a[0]), "+v"(a[1]), "+v"(a[2]), "+v"(a[3]));
}

template<bool FAST>
__device__ __forceinline__ uint32_t ldflag(const uint32_t* p) {
  if constexpr (FAST) {
    uint32_t r;
    asm volatile("global_load_dword %0, %1, off sc0\n\ts_waitcnt vmcnt(0)"
                 : "=v"(r) : "v"((uint64_t)p));
    return r;
  } else {
    return __hip_atomic_load(p, __ATOMIC_RELAXED, __HIP_MEMORY_SCOPE_AGENT);
  }
}

template<bool FAST>
__device__ __forceinline__ void st4(uint32_t* p, uint32_t v) {
  if constexpr (FAST)
    asm volatile("global_store_dword %0, %1, off sc0"
                 :: "v"((uint64_t)p), "v"(v) : "memory");
  else
    __hip_atomic_store(p, v, __ATOMIC_RELAXED, __HIP_MEMORY_SCOPE_AGENT);
}

template<bool FAST>
__device__ __forceinline__ void st2(uint16_t* p, uint16_t v) {
  if constexpr (FAST)
    asm volatile("global_store_short %0, %1, off sc0"
                 :: "v"((uint64_t)p), "v"((uint32_t)v) : "memory");
  else
    __hip_atomic_store(p, v, __ATOMIC_RELAXED, __HIP_MEMORY_SCOPE_AGENT);
}

__device__ __forceinline__ float sigm(float x)  { return 1.0f / (1.0f + __expf(-x)); }
__device__ __forceinline__ float tanh_(float x) { return 1.0f - 2.0f / (1.0f + __expf(2.0f * x)); }

template<bool FAST>
__device__ __forceinline__ void body(
    const float* __restrict__ x,
    const float* __restrict__ Wih1, const float* __restrict__ Whh1,
    const float* __restrict__ bih1, const float* __restrict__ bhh1,
    const float* __restrict__ W1,   const float* __restrict__ b1,
    const float* __restrict__ Wih2, const float* __restrict__ Whh2,
    const float* __restrict__ bih2, const float* __restrict__ bhh2,
    float* __restrict__ out,
    uint32_t* __restrict__ bar,
    uint16_t* __restrict__ hbuf,
    uint16_t (&hsh)[32][16], float (&osh)[32][16],
    uint16_t (&hstage)[32][256], uint16_t (&hstage2)[32][256])
{
  const int tid = threadIdx.x;
  const int l   = tid & 63;
  const int w   = tid >> 6;
  const int blk = blockIdx.x;
  const int gid = (blk & 7) | ((blk >> 7) << 3);   // group: same blk%8 (XCD locality)
  const int mid = (blk >> 3) & 15;
  const int bg  = gid * 32;
  const int c0  = mid * 16 + w * 4;

  const int nl   = l & 15;
  const int kc   = l >> 4;
  const int gate = nl >> 2;
  const int cm   = nl & 3;
  const int colg = c0 + cm;
  const int grow = gate * H_ + colg;

  const int POLL_MAX = FAST ? 50000 : 2000000;

  // flags: one 32B sector per wave-flag; 2 KiB per group
  uint32_t* flags = bar + (size_t)gid * 512;
  const int myflag = (mid * 4 + w) * 8;

  uint16_t* slot0 = hbuf;
  uint16_t* slot1 = hbuf + (size_t)B_ * H_;
  uint16_t* slot2 = hbuf + (size_t)2 * B_ * H_;

  auto arrive = [&](int target) {
    asm volatile("s_waitcnt vmcnt(0)" ::: "memory");   // my stores are in L2/MALL
    if (l == 0) st4<FAST>(&flags[myflag], (uint32_t)target);
  };
  auto poll = [&](int target) {
    int g = 0;
    while ((int)ldflag<FAST>(&flags[l * 8]) < target) {
      __builtin_amdgcn_s_sleep(1);
      if (++g > POLL_MAX) break;  // fail-wrong, not hang
    }
    asm volatile("" ::: "memory");
  };
  auto ldsbar = [&]() {
    asm volatile("s_waitcnt lgkmcnt(0)\n\ts_barrier" ::: "memory");
  };

  // cooperative stage of a 32x256 bf16 peer tile into LDS, chunk-XOR swizzled.
  // thread: row = tid>>3, 64B (4 chunks of 16B) at chunk base (tid&7)*4.
  auto stage_to = [&](uint16_t (&dst)[32][256], const uint16_t* hs) {
    const int rb_ = tid >> 3;
    const int cb_ = (tid & 7) * 4;
    const uint16_t* src = hs + (size_t)(bg + rb_) * H_ + cb_ * 8;
    if constexpr (FAST) {
      u32x4 v[4];
#pragma unroll
      for (int i = 0; i < 4; ++i)
        asm volatile("global_load_dwordx4 %0, %1, off sc0"
                     : "=v"(v[i]) : "v"((uint64_t)(src + i * 8)));
      fence4u(v);
#pragma unroll
      for (int i = 0; i < 4; ++i)
        *(u32x4*)&dst[rb_][(((cb_ + i) ^ (rb_ & 7)) * 8)] = v[i];
    } else {
#pragma unroll
      for (int i = 0; i < 4; ++i) {
        union { uint64_t u[2]; u32x4 v; } r;
        const uint64_t* q = (const uint64_t*)(src + i * 8);
        r.u[0] = __hip_atomic_load(q,     __ATOMIC_RELAXED, __HIP_MEMORY_SCOPE_AGENT);
        r.u[1] = __hip_atomic_load(q + 1, __ATOMIC_RELAXED, __HIP_MEMORY_SCOPE_AGENT);
        *(u32x4*)&dst[rb_][(((cb_ + i) ^ (rb_ & 7)) * 8)] = r.v;
      }
    }
  };
  // A-fragment read back (swizzle-matched): h[row][kt*32+kc*8 ..+8]
  auto frag = [&](uint16_t (&src)[32][256], int mt, int kt) -> short8 {
    const int row = mt * 16 + nl;
    const int ch  = (kt * 4 + kc) ^ (row & 7);
    return *(const short8*)&src[row][ch * 8];
  };

  // ---- encoder weight fragments (B-operand: lane = W[n=nl][k=kc*8+j]) ----
  short8 fwa[8], fwb[8];
#pragma unroll
  for (int kt = 0; kt < 8; ++kt) {
    fwa[kt] = load8f_bf(Wih1 + (size_t)grow * H_ + kt * 32 + kc * 8);
    fwb[kt] = load8f_bf(Whh1 + (size_t)grow * H_ + kt * 32 + kc * 8);
  }
  float bias = bih1[grow] + bhh1[grow];

  float cst[2][4];
#pragma unroll
  for (int mt = 0; mt < 2; ++mt)
#pragma unroll
    for (int r = 0; r < 4; ++r) cst[mt][r] = 0.0f;

  // gate math + LDS gather-write (hn only for r==gate; each (mt,kc,gate,cm) is unique)
  auto epi = [&](const f32x4* acc, float bias_, bool wout) {
    const int rb = (l & 48) | cm;
#pragma unroll
    for (int mt = 0; mt < 2; ++mt) {
      float hn = 0.f;
#pragma unroll
      for (int r = 0; r < 4; ++r) {
        float z = acc[mt][r] + bias_;
        float a = (gate == 2) ? tanh_(z) : sigm(z);
        float ti = __shfl(a, rb,      64);
        float tf = __shfl(a, rb | 4,  64);
        float tg = __shfl(a, rb | 8,  64);
        float to = __shfl(a, rb | 12, 64);
        float cn = tf * cst[mt][r] + ti * tg;
        cst[mt][r] = cn;
        if (r == gate) hn = to * tanh_(cn);
      }
      hsh[mt * 16 + kc * 4 + gate][w * 4 + cm] = (uint16_t)f2bf(hn);
      if (wout) osh[mt * 16 + kc * 4 + gate][w * 4 + cm] = hn;
    }
  };

  const int gb = tid >> 3;          // gather: b_loc 0..31
  const int gc = tid & 7;           // 4B chunk within the 32B row-chunk

  // x-part MFMAs for step t (independent of h) -> runs post-flag, pre-poll
  f32x4 accN[2];
  auto xmfma = [&](int t) {
#pragma unroll
    for (int mt = 0; mt < 2; ++mt) {
      f32x4 a = {0.f, 0.f, 0.f, 0.f};
      const float* xr = x + ((size_t)(bg + mt * 16 + nl) * T_ + t) * H_ + kc * 8;
#pragma unroll
      for (int kt = 0; kt < 8; ++kt) {
        short8 af = load8f_bf(xr + kt * 32);
        a = __builtin_amdgcn_mfma_f32_16x16x32_bf16(af, fwa[kt], a, 0, 0, 0);
      }
      accN[mt] = a;
    }
  };
  xmfma(0);

  // ---------------- encoder ----------------
  for (int t = 0; t < T_; ++t) {
    f32x4 acc[2] = { accN[0], accN[1] };
    if (t > 0) {
      poll(t);
      const uint16_t* hs = (t & 1) ? slot1 : slot0;
      stage_to(hstage, hs);
      ldsbar();
#pragma unroll
      for (int mt = 0; mt < 2; ++mt)
#pragma unroll
        for (int kt = 0; kt < 8; ++kt)
          acc[mt] = __builtin_amdgcn_mfma_f32_16x16x32_bf16(frag(hstage, mt, kt), fwb[kt], acc[mt], 0, 0, 0);
    }
    epi(acc, bias, false);
    ldsbar();
    uint16_t* hw = ((t + 1) & 1) ? slot1 : slot0;
    {
      uint32_t hv = *(const uint32_t*)&hsh[gb][gc * 2];
      st4<FAST>((uint32_t*)&hw[(size_t)(bg + gb) * H_ + mid * 16 + gc * 2], hv);
    }
    arrive(t + 1);
    if (t + 1 < T_) xmfma(t + 1);   // overlapped with peers' arrival
  }

  // ---------------- x_end = h1 @ W1.T + b1  (h1 in slot0) ----------------
  poll(T_);
  stage_to(hstage, slot0);          // hstage = h1; kept resident for decoder t0
  ldsbar();
  {
    const int xcol = mid * 16 + nl;
    short8 fw1[8];
#pragma unroll
    for (int kt = 0; kt < 8; ++kt)
      fw1[kt] = load8f_bf(W1 + (size_t)xcol * H_ + kt * 32 + kc * 8);
    f32x4 acc[2] = { {0.f,0.f,0.f,0.f}, {0.f,0.f,0.f,0.f} };
#pragma unroll
    for (int mt = 0; mt < 2; ++mt)
#pragma unroll
      for (int kt = 0; kt < 8; ++kt)
        acc[mt] = __builtin_amdgcn_mfma_f32_16x16x32_bf16(frag(hstage, mt, kt), fw1[kt], acc[mt], 0, 0, 0);
    float bb = b1[xcol];
    if (w == 0) {  // one wave writes x_end (scattered 2B, one-time)
#pragma unroll
      for (int mt = 0; mt < 2; ++mt)
#pragma unroll
        for (int r = 0; r < 4; ++r) {
          int b = bg + mt * 16 + kc * 4 + r;
          st2<FAST>(&slot2[(size_t)b * H_ + mid * 16 + nl], (uint16_t)f2bf(acc[mt][r] + bb));
        }
    }
  }
  arrive(T_ + 1);

  // decoder weight prep in the window
  short8 fwa2[8], fwb2[8], fws[8];
#pragma unroll
  for (int kt = 0; kt < 8; ++kt) {
    const float* pa = Wih2 + (size_t)grow * H_ + kt * 32 + kc * 8;
    const float* pb = Whh2 + (size_t)grow * H_ + kt * 32 + kc * 8;
    fwa2[kt] = load8f_bf(pa);
    fwb2[kt] = load8f_bf(pb);
    fws[kt]  = load8f_bf_sum(pa, pb);   // bf16(Wih2+Whh2), summed in fp32
  }
  bias = bih2[grow] + bhh2[grow];
  poll(T_ + 1);

  // ---------------- decoder t=0 (x_end w/ fwa2, h1 w/ fwb2) ----------------
  {
    stage_to(hstage2, slot2);       // x_end; h1 still in hstage
    ldsbar();
    f32x4 acc[2] = { {0.f,0.f,0.f,0.f}, {0.f,0.f,0.f,0.f} };
#pragma unroll
    for (int mt = 0; mt < 2; ++mt)
#pragma unroll
      for (int kt = 0; kt < 8; ++kt) {
        acc[mt] = __builtin_amdgcn_mfma_f32_16x16x32_bf16(frag(hstage2, mt, kt), fwa2[kt], acc[mt], 0, 0, 0);
        acc[mt] = __builtin_amdgcn_mfma_f32_16x16x32_bf16(frag(hstage,  mt, kt), fwb2[kt], acc[mt], 0, 0, 0);
      }
    epi(acc, bias, true);
    ldsbar();
    uint32_t hv = *(const uint32_t*)&hsh[gb][gc * 2];
    uint64_t ov = *(const uint64_t*)&osh[gb][gc * 2];
    st4<FAST>((uint32_t*)&slot1[(size_t)(bg + gb) * H_ + mid * 16 + gc * 2], hv);
    arrive(T_ + 2);
    *(uint64_t*)&out[((size_t)(bg + gb) * T_ + (T_ - 2)) * H_ + mid * 16 + gc * 2] = ov;
  }

  // ---------------- decoder t>=1 (merged weights; x_t == h_{t-1}) ----------------
  for (int t = 1; t < T_; ++t) {
    poll(T_ + 1 + t);
    const uint16_t* hs = (t & 1) ? slot1 : slot0;
    stage_to(hstage, hs);
    ldsbar();
    f32x4 acc[2] = { {0.f,0.f,0.f,0.f}, {0.f,0.f,0.f,0.f} };
#pragma unroll
    for (int mt = 0; mt < 2; ++mt)
#pragma unroll
      for (int kt = 0; kt < 8; ++kt)
        acc[mt] = __builtin_amdgcn_mfma_f32_16x16x32_bf16(frag(hstage, mt, kt), fws[kt], acc[mt], 0, 0, 0);

    epi(acc, bias, true);
    ldsbar();
    const int j = (t == T_ - 1) ? (T_ - 1) : (T_ - 2 - t);
    uint32_t hv = *(const uint32_t*)&hsh[gb][gc * 2];
    uint64_t ov = *(const uint64_t*)&osh[gb][gc * 2];
    if (t + 1 < T_) {
      uint16_t* hw = ((t + 1) & 1) ? slot1 : slot0;
      st4<FAST>((uint32_t*)&hw[(size_t)(bg + gb) * H_ + mid * 16 + gc * 2], hv);
      arrive(T_ + 2 + t);
    }
    *(uint64_t*)&out[((size_t)(bg + gb) * T_ + j) * H_ + mid * 16 + gc * 2] = ov;
  }
}

__global__ __launch_bounds__(256, 1) void encdec_kernel(
    const float* __restrict__ x,
    const float* __restrict__ Wih1, const float* __restrict__ Whh1,
    const float* __restrict__ bih1, const float* __restrict__ bhh1,
    const float* __restrict__ W1,   const float* __restrict__ b1,
    const float* __restrict__ Wih2, const float* __restrict__ Whh2,
    const float* __restrict__ bih2, const float* __restrict__ bhh2,
    float* __restrict__ out,
    uint32_t* __restrict__ bar,
    uint16_t* __restrict__ hbuf)
{
  __shared__ __align__(16) uint16_t hstage [32][256];  // 16KB peer-h stage
  __shared__ __align__(16) uint16_t hstage2[32][256];  // 16KB (decoder t0 only)
  __shared__ uint16_t hsh[32][16];  // block's h tile (b_loc x col16), bf16
  __shared__ float    osh[32][16];  // block's out tile, fp32 (decoder)

  const int tid = threadIdx.x;
  const int l   = tid & 63;
  const int blk = blockIdx.x;
  const int gid = (blk & 7) | ((blk >> 7) << 3);
  const int mid = (blk >> 3) & 15;

  uint32_t* xw = bar + (size_t)gid * 512;  // words mod 8 in {1,2,3}: never touched by body

  // --- phase 1: XCC-ID consensus (agent scope; reliable) ---
  // s_getreg hwreg(HW_REG_XCC_ID=20, offset=0, size=4) -> imm 20|(3<<11)
  const uint32_t my_xcc = (uint32_t)__builtin_amdgcn_s_getreg(6164) & 0xffu;
  if (tid == 0)
    __hip_atomic_store(&xw[mid * 8 + 1], 0x100u | my_xcc,
                       __ATOMIC_RELAXED, __HIP_MEMORY_SCOPE_AGENT);
  uint32_t pv = 0; int g = 0; bool seen = true;
  for (;;) {
    pv = __hip_atomic_load(&xw[(l & 15) * 8 + 1],
                           __ATOMIC_RELAXED, __HIP_MEMORY_SCOPE_AGENT);
    if (pv & 0x100u) break;
    __builtin_amdgcn_s_sleep(1);
    if (++g > 1000000) { seen = false; break; }
  }
  const bool same_xcd = __all((int)(seen && ((pv & 0xffu) == my_xcc)));

  // --- phase 2: sc0 visibility self-test (bounded; only if same XCD) ---
  int verdict = 0;
  if (same_xcd) {
    if (tid == 0) st4<true>(&xw[mid * 8 + 2], 0xA5A5u);
    g = 0; bool s2 = true;
    for (;;) {
      uint32_t qv = ldflag<true>(&xw[(l & 15) * 8 + 2]);
      if (qv == 0xA5A5u) break;
      __builtin_amdgcn_s_sleep(1);
      if (++g > 20000) { s2 = false; break; }   // ~ms bound; normal: <100 iters
    }
    verdict = __all((int)s2) ? 1 : 0;
  }

  // --- phase 3: unanimous-verdict exchange (agent scope; reliable) ---
  if (tid == 0)
    __hip_atomic_store(&xw[mid * 8 + 3], 0x200u | (uint32_t)verdict,
                       __ATOMIC_RELAXED, __HIP_MEMORY_SCOPE_AGENT);
  uint32_t vv = 0; g = 0; seen = true;
  for (;;) {
    vv = __hip_atomic_load(&xw[(l & 15) * 8 + 3],
                           __ATOMIC_RELAXED, __HIP_MEMORY_SCOPE_AGENT);
    if (vv & 0x200u) break;
    __builtin_amdgcn_s_sleep(1);
    if (++g > 1000000) { seen = false; break; }
  }
  const bool fast = __all((int)(seen && (vv & 1u)));

  if (fast)
    body<true>(x, Wih1, Whh1, bih1, bhh1, W1, b1, Wih2, Whh2, bih2, bhh2,
               out, bar, hbuf, hsh, osh, hstage, hstage2);
  else
    body<false>(x, Wih1, Whh1, bih1, bhh1, W1, b1, Wih2, Whh2, bih2, bhh2,
                out, bar, hbuf, hsh, osh, hstage, hstage2);
}

extern "C" void kernel_launch(void* const* d_in, const int* in_sizes, int n_in,
                              void* d_out, int out_size, void* d_ws, size_t ws_size,
                              hipStream_t stream) {
  const float* x    = (const float*)d_in[0];
  const float* Wih1 = (const float*)d_in[1];
  const float* Whh1 = (const float*)d_in[2];
  const float* bih1 = (const float*)d_in[3];
  const float* bhh1 = (const float*)d_in[4];
  const float* W1   = (const float*)d_in[5];
  const float* b1   = (const float*)d_in[6];
  const float* Wih2 = (const float*)d_in[7];
  const float* Whh2 = (const float*)d_in[8];
  const float* bih2 = (const float*)d_in[9];
  const float* bhh2 = (const float*)d_in[10];
  float* out = (float*)d_out;

  uint32_t* bar  = (uint32_t*)d_ws;                   // 16 groups x 2 KiB flag/consensus regions
  uint16_t* hbuf = (uint16_t*)((char*)d_ws + 32768);  // 3 bf16 (B,H) slots

  hipLaunchKernelGGL(encdec_kernel, dim3(256), dim3(256), 0, stream,
                     x, Wih1, Whh1, bih1, bhh1, W1, b1, Wih2, Whh2, bih2, bhh2,
                     out, bar, hbuf);
}